// Round 6
// baseline (2568.638 us; speedup 1.0000x reference)
//
#include <hip/hip_runtime.h>

// GIN_MLP: 2x GIN conv (N=100000, E=1.6M, H=128) + per-batch context MLP (B=4096).
// Device-built dst-CSR (rank-based, atomic-free scatter) -> fused aggregate+GEMM
// -> per-batch MLP. All f32 (R5's bf16 gather regressed: wall is not bytes).
// R6: divergence-free stage 1. Edge records carry dst (int4), so each 32-lane
// laneset walks its chunk with a UNIFORM trip count (no row-boundary control
// flow, no cross-half wave divergence), 4 independent float4 gathers in flight,
// per-edge LDS atomicAdd into a permuted conflict-free layout
// (feature lane*4+i at slot r*128 + i*32 + lane). Stage 2 de-permutes via regs.

#define CONV_NPB 32

__global__ void prep_transpose(const float* __restrict__ W1, const float* __restrict__ W2,
                               const float* __restrict__ Wc1, const float* __restrict__ Wc2,
                               float* __restrict__ Wt1, float* __restrict__ Wt2,
                               float* __restrict__ Wc1t, float* __restrict__ Wc2t) {
  int i = blockIdx.x * blockDim.x + threadIdx.x;
  if (i < 16384) {
    int f = i >> 7, k = i & 127;
    Wt1[k * 128 + f] = W1[i];
  } else if (i < 32768) {
    int j = i - 16384; int f = j >> 7, k = j & 127;
    Wt2[k * 128 + f] = W2[j];
  } else if (i < 81920) {
    int j = i - 32768; int f = j / 384, k = j % 384;
    Wc1t[k * 128 + f] = Wc1[j];
  } else if (i < 90112) {
    int j = i - 81920; int f = j >> 7, k = j & 127;
    Wc2t[k * 64 + f] = Wc2[j];
  }
}

// counts per-dst degree AND records each edge's arrival rank (makes scatter atomic-free)
__global__ void hist_kernel(const int* __restrict__ dst, int* __restrict__ cnt,
                            int* __restrict__ rank, int E) {
  int e = blockIdx.x * blockDim.x + threadIdx.x;
  if (e < E) rank[e] = atomicAdd(&cnt[dst[e]], 1);
}

// per-2048-chunk exclusive scan; bsum[b] = chunk total
__global__ void scan1_kernel(const int* __restrict__ cnt, int* __restrict__ rowptr,
                             int* __restrict__ bsum, int n) {
  __shared__ int smem[256];
  const int t = threadIdx.x;
  const int base = blockIdx.x * 2048 + t * 8;
  int v[8];
  int s = 0;
#pragma unroll
  for (int j = 0; j < 8; ++j) {
    int idx = base + j;
    v[j] = (idx < n) ? cnt[idx] : 0;
    s += v[j];
  }
  smem[t] = s;
  __syncthreads();
  for (int off = 1; off < 256; off <<= 1) {
    int add = (t >= off) ? smem[t - off] : 0;
    __syncthreads();
    smem[t] += add;
    __syncthreads();
  }
  int run = smem[t] - s;
  if (t == 255) bsum[blockIdx.x] = smem[255];
#pragma unroll
  for (int j = 0; j < 8; ++j) {
    int idx = base + j;
    if (idx < n) rowptr[idx] = run;
    run += v[j];
  }
}

// 64-lane shuffle scan (nchunk=49 fits)
__global__ void scan2_kernel(int* __restrict__ bsum, int nb) {
  const int t = threadIdx.x;
  if (nb <= 64) {
    const int orig = (t < nb) ? bsum[t] : 0;
    int v = orig;
#pragma unroll
    for (int off = 1; off < 64; off <<= 1) {
      int u = __shfl_up(v, off);
      if (t >= off) v += u;
    }
    if (t < nb) bsum[t] = v - orig;
  } else if (t == 0) {
    int run = 0;
    for (int i = 0; i < nb; ++i) { int v = bsum[i]; bsum[i] = run; run += v; }
  }
}

__global__ void scan3_kernel(int* __restrict__ rowptr, const int* __restrict__ bsum,
                             int n, int E) {
  int i = blockIdx.x * blockDim.x + threadIdx.x;
  if (i < n) rowptr[i] += bsum[i >> 11];
  if (i == 0) rowptr[n] = E;
}

// atomic-free scatter: pos = rowptr[dst] + rank; record (src, w, dst) per edge
__global__ void scatter_kernel(const int* __restrict__ src, const int* __restrict__ dst,
                               const float* __restrict__ w, const int* __restrict__ rowptr,
                               const int* __restrict__ rank, int4* __restrict__ epack, int E) {
  int e = blockIdx.x * blockDim.x + threadIdx.x;
  if (e < E) {
    const int d = dst[e];
    const int pos = rowptr[d] + rank[e];
    epack[pos] = make_int4(src[e], __float_as_int(w[e]), d, 0);
  }
}

// Stage 1: block's 32 rows = contiguous edge range split into 8 equal laneset
// chunks; UNIFORM loop count (chunk) across all lanesets -> no wave divergence.
// Per iteration: 4 predicated int4 edge loads, 4 independent float4 row
// gathers, then per-edge LDS atomicAdd into permuted layout
// slot(r, lane, i) = r*128 + i*32 + lane  (bank = lane -> conflict-free).
// Stage 2: de-permute via regs + finalize (1+eps)x + agg/deg into standard
// layout. Stage 3: 32x128 @ 128x128 f32 GEMM (ds_read_b128 on standard layout).
__launch_bounds__(256, 8)
__global__ void conv_kernel(const float* __restrict__ xin, float* __restrict__ xout,
                            const int* __restrict__ rowptr, const int4* __restrict__ epack,
                            const float* __restrict__ Wt,
                            const float* __restrict__ bias, const float* __restrict__ eps,
                            int epsidx, int dorelu, int zerorow0, int n) {
  __shared__ float xm[CONV_NPB * 128];
  __shared__ int rp_s[CONV_NPB + 1];
  const int t = threadIdx.x;
  const int nb = blockIdx.x * CONV_NPB;
  const float epsv = 1.0f + eps[epsidx];

  // zero accumulator tile + cache rowptr slice
#pragma unroll
  for (int i = 0; i < 4; ++i)
    *(float4*)&xm[(t + i * 256) * 4] = make_float4(0.f, 0.f, 0.f, 0.f);
  if (t <= CONV_NPB) {
    int node = nb + t;
    rp_s[t] = rowptr[node <= n ? node : n];
  }
  __syncthreads();

  // ---- stage 1: divergence-free edge-parallel gather ----
  {
    const int L = t >> 5;          // laneset 0..7
    const int lane = t & 31;
    const int f0 = lane * 4;
    const int e0 = rp_s[0], eT = rp_s[CONV_NPB];
    const int total = eT - e0;
    const int chunk = (total + 7) >> 3;          // uniform across block
    const int jb = e0 + L * chunk;
    const int je = min(jb + chunk, eT);
    for (int i = 0; i < chunk; i += 4) {
      int4 p[4];
      float4 a[4];
#pragma unroll
      for (int u = 0; u < 4; ++u) {
        const int idx = jb + i + u;
        p[u] = (idx < je) ? epack[idx] : make_int4(0, 0, nb, 0);  // w=0 dummy
      }
#pragma unroll
      for (int u = 0; u < 4; ++u)
        a[u] = *(const float4*)&xin[(size_t)p[u].x * 128 + f0];
#pragma unroll
      for (int u = 0; u < 4; ++u) {
        const float wv = __int_as_float(p[u].y);
        const int r = p[u].z - nb;
        float* bp = &xm[r * 128 + lane];
        atomicAdd(bp + 0,  wv * a[u].x);
        atomicAdd(bp + 32, wv * a[u].y);
        atomicAdd(bp + 64, wv * a[u].z);
        atomicAdd(bp + 96, wv * a[u].w);
      }
    }
  }
  __syncthreads();

  // ---- stage 2: de-permute + finalize (1+eps)*x + agg/deg ----
  {
    float4 m[4];
#pragma unroll
    for (int q = 0; q < 4; ++q) {
      const int task = t + q * 256;             // 32 rows x 32 fgroups
      const int r = task >> 5;
      const int fg = task & 31;
      m[q].x = xm[r * 128 + fg];
      m[q].y = xm[r * 128 + 32 + fg];
      m[q].z = xm[r * 128 + 64 + fg];
      m[q].w = xm[r * 128 + 96 + fg];
    }
    __syncthreads();
#pragma unroll
    for (int q = 0; q < 4; ++q) {
      const int task = t + q * 256;
      const int r = task >> 5;
      const int fg = task & 31;
      const int f0 = fg * 4;
      const int node = nb + r;
      float4 v = make_float4(0.f, 0.f, 0.f, 0.f);
      if (node < n) {
        const int d = rp_s[r + 1] - rp_s[r];
        const float rdeg = 1.0f / (float)(d > 1 ? d : 1);
        const float4 xv = *(const float4*)&xin[(size_t)node * 128 + f0];
        v.x = epsv * xv.x + m[q].x * rdeg;
        v.y = epsv * xv.y + m[q].y * rdeg;
        v.z = epsv * xv.z + m[q].z * rdeg;
        v.w = epsv * xv.w + m[q].w * rdeg;
      }
      *(float4*)&xm[r * 128 + f0] = v;
    }
  }
  __syncthreads();

  // ---- stage 3: GEMM, thread tile = 4 rows x 4 features ----
  {
    const int fg = t & 31;
    const int rg = t >> 5;
    const int f0 = fg * 4;
    const int r0 = rg * 4;
    float4 acc[4];
#pragma unroll
    for (int r = 0; r < 4; ++r) acc[r] = make_float4(0.f, 0.f, 0.f, 0.f);
    for (int k = 0; k < 128; k += 4) {
      const float4 w0 = *(const float4*)&Wt[(k + 0) * 128 + f0];
      const float4 w1 = *(const float4*)&Wt[(k + 1) * 128 + f0];
      const float4 w2 = *(const float4*)&Wt[(k + 2) * 128 + f0];
      const float4 w3 = *(const float4*)&Wt[(k + 3) * 128 + f0];
#pragma unroll
      for (int r = 0; r < 4; ++r) {
        const float4 xv = *(const float4*)&xm[(r0 + r) * 128 + k];
        acc[r].x += xv.x * w0.x + xv.y * w1.x + xv.z * w2.x + xv.w * w3.x;
        acc[r].y += xv.x * w0.y + xv.y * w1.y + xv.z * w2.y + xv.w * w3.y;
        acc[r].z += xv.x * w0.z + xv.y * w1.z + xv.z * w2.z + xv.w * w3.z;
        acc[r].w += xv.x * w0.w + xv.y * w1.w + xv.z * w2.w + xv.w * w3.w;
      }
    }
    const float4 bv = *(const float4*)&bias[f0];
#pragma unroll
    for (int r = 0; r < 4; ++r) {
      const int node = nb + r0 + r;
      if (node < n) {
        float4 v;
        v.x = acc[r].x + bv.x;
        v.y = acc[r].y + bv.y;
        v.z = acc[r].z + bv.z;
        v.w = acc[r].w + bv.w;
        if (dorelu) {
          v.x = fmaxf(v.x, 0.f); v.y = fmaxf(v.y, 0.f);
          v.z = fmaxf(v.z, 0.f); v.w = fmaxf(v.w, 0.f);
        }
        if (zerorow0 && node == 0) { v.x = 0.f; v.y = 0.f; v.z = 0.f; v.w = 0.f; }
        *(float4*)&xout[(size_t)node * 128 + f0] = v;
      }
    }
  }
}

// One block (128 thr) per batch element: gather ing1/ing2/ctx into LDS, MLP 384->128->64->1.
__launch_bounds__(128, 4)
__global__ void final_kernel(const float* __restrict__ x2, const int* __restrict__ indices,
                             const float* __restrict__ Wc1t, const float* __restrict__ bc1,
                             const float* __restrict__ Wc2t, const float* __restrict__ bc2,
                             const float* __restrict__ Wc3, const float* __restrict__ bc3,
                             float* __restrict__ out) {
  __shared__ float ysm[384];
  __shared__ float h1s[128];
  const int b = blockIdx.x;
  const int t = threadIdx.x;
  const int* ind = indices + (size_t)b * 23;

  {
    const int i0 = ind[0];
    const int i1 = ind[1];
    ysm[t] = x2[(size_t)i0 * 128 + t];
    ysm[128 + t] = x2[(size_t)i1 * 128 + t];
    float cs = 0.f;
    int cc = 0;
#pragma unroll
    for (int j = 0; j < 20; ++j) {
      const int cj = ind[3 + j];
      cc += (cj > 0) ? 1 : 0;
      cs += x2[(size_t)cj * 128 + t];
    }
    ysm[256 + t] = cs / (float)(cc > 0 ? cc : 1);
  }
  __syncthreads();

  {
    float acc = bc1[t];
    for (int k = 0; k < 384; k += 4) {
      const float4 yv = *(const float4*)&ysm[k];
      acc += yv.x * Wc1t[(k + 0) * 128 + t];
      acc += yv.y * Wc1t[(k + 1) * 128 + t];
      acc += yv.z * Wc1t[(k + 2) * 128 + t];
      acc += yv.w * Wc1t[(k + 3) * 128 + t];
    }
    h1s[t] = fmaxf(acc, 0.f);
  }
  __syncthreads();

  if (t < 64) {
    float acc = bc2[t];
    for (int k = 0; k < 128; k += 4) {
      const float4 hv = *(const float4*)&h1s[k];
      acc += hv.x * Wc2t[(k + 0) * 64 + t];
      acc += hv.y * Wc2t[(k + 1) * 64 + t];
      acc += hv.z * Wc2t[(k + 2) * 64 + t];
      acc += hv.w * Wc2t[(k + 3) * 64 + t];
    }
    float v = fmaxf(acc, 0.f) * Wc3[t];
#pragma unroll
    for (int o = 32; o > 0; o >>= 1) v += __shfl_down(v, o);
    if (t == 0) out[b] = v + bc3[0];
  }
}

extern "C" void kernel_launch(void* const* d_in, const int* in_sizes, int n_in,
                              void* d_out, int out_size, void* d_ws, size_t ws_size,
                              hipStream_t stream) {
  const int* indices = (const int*)d_in[0];
  const int* src = (const int*)d_in[1];
  const int* dst = (const int*)d_in[2];
  const float* w = (const float*)d_in[3];
  const float* ndata = (const float*)d_in[4];
  const float* W1 = (const float*)d_in[5];
  const float* b1 = (const float*)d_in[6];
  const float* W2 = (const float*)d_in[7];
  const float* b2 = (const float*)d_in[8];
  const float* eps = (const float*)d_in[9];
  const float* Wc1 = (const float*)d_in[10];
  const float* bc1 = (const float*)d_in[11];
  const float* Wc2 = (const float*)d_in[12];
  const float* bc2 = (const float*)d_in[13];
  const float* Wc3 = (const float*)d_in[14];
  const float* bc3 = (const float*)d_in[15];
  float* out = (float*)d_out;

  const int E = in_sizes[1];
  const int N = in_sizes[4] / 128;
  const int B = in_sizes[0] / 23;

  char* ws = (char*)d_ws;
  size_t off = 0;
  auto alloc = [&](size_t bytes) -> char* {
    char* p = ws + off;
    off = (off + bytes + 255) & ~(size_t)255;
    return p;
  };
  int* cnt = (int*)alloc((size_t)N * 4);
  int* rowptr = (int*)alloc((size_t)(N + 1) * 4);
  int* rank = (int*)alloc((size_t)E * 4);
  int* bsum = (int*)alloc(256 * 4);
  int4* epack = (int4*)alloc((size_t)E * 16);
  float* x1 = (float*)alloc((size_t)N * 128 * 4);
  float* x2 = (float*)alloc((size_t)N * 128 * 4);
  float* Wt1 = (float*)alloc(16384 * 4);
  float* Wt2 = (float*)alloc(16384 * 4);
  float* Wc1t = (float*)alloc(49152 * 4);
  float* Wc2t = (float*)alloc(8192 * 4);

  hipMemsetAsync(cnt, 0, (size_t)N * 4, stream);

  prep_transpose<<<(90112 + 255) / 256, 256, 0, stream>>>(W1, W2, Wc1, Wc2, Wt1, Wt2, Wc1t, Wc2t);
  hist_kernel<<<(E + 255) / 256, 256, 0, stream>>>(dst, cnt, rank, E);
  const int nchunk = (N + 2047) / 2048;
  scan1_kernel<<<nchunk, 256, 0, stream>>>(cnt, rowptr, bsum, N);
  scan2_kernel<<<1, 64, 0, stream>>>(bsum, nchunk);
  scan3_kernel<<<(N + 255) / 256, 256, 0, stream>>>(rowptr, bsum, N, E);
  scatter_kernel<<<(E + 255) / 256, 256, 0, stream>>>(src, dst, w, rowptr, rank, epack, E);

  const int nconv = (N + CONV_NPB - 1) / CONV_NPB;
  conv_kernel<<<nconv, 256, 0, stream>>>(ndata, x1, rowptr, epack, Wt1, b1, eps, 0, 1, 0, N);
  conv_kernel<<<nconv, 256, 0, stream>>>(x1, x2, rowptr, epack, Wt2, b2, eps, 1, 0, 1, N);

  final_kernel<<<B, 128, 0, stream>>>(x2, indices, Wc1t, bc1, Wc2t, bc2, Wc3, bc3, out);
}

// Round 7
// 607.039 us; speedup vs baseline: 4.2314x; 4.2314x over previous
//
#include <hip/hip_runtime.h>

// GIN_MLP: 2x GIN conv (N=100000, E=1.6M, H=128) + per-batch context MLP (B=4096).
// Device-built dst-CSR (rank-based atomic-free scatter) -> fused aggregate+GEMM
// -> per-batch MLP. All f32.
// R7: 8-ALIGNED PADDED CSR. Each row's edge segment is padded to a multiple of
// 8 with (src=0,w=0) dummies, so every 8-edge batch lies inside ONE row: the
// stage-1 hot loop is straight-line (4 int4 descriptor loads + 8 independent
// float4 gathers + 32 FMA), no predication, no remainder loop, row-boundary
// check once per batch. Register acc flushes to LDS (permuted, bank=lane,
// conflict-free) only at row transitions; stage 2 de-permutes (verified in R6).

#define CONV_NPB 32

__global__ void prep_transpose(const float* __restrict__ W1, const float* __restrict__ W2,
                               const float* __restrict__ Wc1, const float* __restrict__ Wc2,
                               float* __restrict__ Wt1, float* __restrict__ Wt2,
                               float* __restrict__ Wc1t, float* __restrict__ Wc2t) {
  int i = blockIdx.x * blockDim.x + threadIdx.x;
  if (i < 16384) {
    int f = i >> 7, k = i & 127;
    Wt1[k * 128 + f] = W1[i];
  } else if (i < 32768) {
    int j = i - 16384; int f = j >> 7, k = j & 127;
    Wt2[k * 128 + f] = W2[j];
  } else if (i < 81920) {
    int j = i - 32768; int f = j / 384, k = j % 384;
    Wc1t[k * 128 + f] = Wc1[j];
  } else if (i < 90112) {
    int j = i - 81920; int f = j >> 7, k = j & 127;
    Wc2t[k * 64 + f] = Wc2[j];
  }
}

// counts per-dst degree AND records each edge's arrival rank (makes scatter atomic-free)
__global__ void hist_kernel(const int* __restrict__ dst, int* __restrict__ cnt,
                            int* __restrict__ rank, int E) {
  int e = blockIdx.x * blockDim.x + threadIdx.x;
  if (e < E) rank[e] = atomicAdd(&cnt[dst[e]], 1);
}

// per-2048-chunk exclusive scan of PADDED counts (ceil(cnt/8)*8); bsum[b] = chunk total
__global__ void scan1_kernel(const int* __restrict__ cnt, int* __restrict__ prow,
                             int* __restrict__ bsum, int n) {
  __shared__ int smem[256];
  const int t = threadIdx.x;
  const int base = blockIdx.x * 2048 + t * 8;
  int v[8];
  int s = 0;
#pragma unroll
  for (int j = 0; j < 8; ++j) {
    int idx = base + j;
    v[j] = (idx < n) ? ((cnt[idx] + 7) & ~7) : 0;
    s += v[j];
  }
  smem[t] = s;
  __syncthreads();
  for (int off = 1; off < 256; off <<= 1) {
    int add = (t >= off) ? smem[t - off] : 0;
    __syncthreads();
    smem[t] += add;
    __syncthreads();
  }
  int run = smem[t] - s;
  if (t == 255) bsum[blockIdx.x] = smem[255];
#pragma unroll
  for (int j = 0; j < 8; ++j) {
    int idx = base + j;
    if (idx < n) prow[idx] = run;
    run += v[j];
  }
}

// 64-lane shuffle scan (nchunk=49 fits); also appends grand total at bsum[nb]
__global__ void scan2_kernel(int* __restrict__ bsum, int nb) {
  const int t = threadIdx.x;
  if (nb <= 64) {
    const int orig = (t < nb) ? bsum[t] : 0;
    int v = orig;
#pragma unroll
    for (int off = 1; off < 64; off <<= 1) {
      int u = __shfl_up(v, off);
      if (t >= off) v += u;
    }
    if (t == nb - 1) bsum[nb] = v;          // inclusive grand total (padded E')
    if (t < nb) bsum[t] = v - orig;
  } else if (t == 0) {
    int run = 0;
    for (int i = 0; i < nb; ++i) { int v = bsum[i]; bsum[i] = run; run += v; }
    bsum[nb] = run;
  }
}

__global__ void scan3_kernel(int* __restrict__ prow, const int* __restrict__ bsum,
                             int n, int nchunk) {
  int i = blockIdx.x * blockDim.x + threadIdx.x;
  if (i < n) prow[i] += bsum[i >> 11];
  if (i == 0) prow[n] = bsum[nchunk];
}

// atomic-free scatter into padded CSR: pos = prow[dst] + rank (epack pre-zeroed,
// so pad slots remain (src=0, w=0) dummies contributing exactly 0)
__global__ void scatter_kernel(const int* __restrict__ src, const int* __restrict__ dst,
                               const float* __restrict__ w, const int* __restrict__ prow,
                               const int* __restrict__ rank, int2* __restrict__ epack, int E) {
  int e = blockIdx.x * blockDim.x + threadIdx.x;
  if (e < E) {
    int pos = prow[dst[e]] + rank[e];
    epack[pos] = make_int2(src[e], __float_as_int(w[e]));
  }
}

// Stage 1: block's 32 rows = contiguous 8-aligned padded edge range, split into
// 8 laneset chunks (multiples of 8). Hot loop per 8-edge batch: 4 int4
// descriptor loads + 8 independent float4 gathers + 32 FMA, straight-line.
// Register acc flushes to LDS (permuted: slot r*128 + 32*i + lane, bank=lane)
// only at row transitions. Stage 2: de-permute + (1+eps)x + agg/deg (deg from
// true cnt). Stage 3: 32x128 @ 128x128 f32 GEMM.
__launch_bounds__(256, 6)
__global__ void conv_kernel(const float* __restrict__ xin, float* __restrict__ xout,
                            const int* __restrict__ prow, const int* __restrict__ cnt,
                            const int2* __restrict__ epack,
                            const float* __restrict__ Wt,
                            const float* __restrict__ bias, const float* __restrict__ eps,
                            int epsidx, int dorelu, int zerorow0, int n) {
  __shared__ float xm[CONV_NPB * 128];
  __shared__ int rp_s[CONV_NPB + 1];
  const int t = threadIdx.x;
  const int nb = blockIdx.x * CONV_NPB;
  const float epsv = 1.0f + eps[epsidx];

  // zero accumulator tile + cache padded rowptr slice
#pragma unroll
  for (int i = 0; i < 4; ++i)
    *(float4*)&xm[(t + i * 256) * 4] = make_float4(0.f, 0.f, 0.f, 0.f);
  if (t <= CONV_NPB) {
    int node = nb + t;
    rp_s[t] = prow[node <= n ? node : n];
  }
  __syncthreads();

  // ---- stage 1: padded 8-batch gather ----
  {
    const int L = t >> 5;          // laneset 0..7
    const int lane = t & 31;
    const int f0 = lane * 4;
    const int e0 = rp_s[0], eT = rp_s[CONV_NPB];
    const int nbat = (eT - e0) >> 3;             // total 8-batches (8-aligned)
    const int chunk = (((nbat + 7) >> 3)) << 3;  // edges per laneset, mult of 8
    const int jb = e0 + L * chunk;
    const int je = min(jb + chunk, eT);
    if (jb < je) {
      const int4* ep4 = (const int4*)epack;      // (src0,w0,src1,w1)
      int r = 0;
      while (rp_s[r + 1] <= jb) ++r;
      float4 acc = make_float4(0.f, 0.f, 0.f, 0.f);
      for (int j = jb; j < je; j += 8) {
        if (rp_s[r + 1] <= j) {                  // new row: flush (permuted, bank=lane)
          float* bp = &xm[r * 128 + lane];
          atomicAdd(bp + 0,  acc.x);
          atomicAdd(bp + 32, acc.y);
          atomicAdd(bp + 64, acc.z);
          atomicAdd(bp + 96, acc.w);
          acc = make_float4(0.f, 0.f, 0.f, 0.f);
          do { ++r; } while (rp_s[r + 1] <= j);
        }
        const int h = j >> 1;
        const int4 q0 = ep4[h + 0];
        const int4 q1 = ep4[h + 1];
        const int4 q2 = ep4[h + 2];
        const int4 q3 = ep4[h + 3];
        const float4 a0 = *(const float4*)&xin[(size_t)q0.x * 128 + f0];
        const float4 a1 = *(const float4*)&xin[(size_t)q0.z * 128 + f0];
        const float4 a2 = *(const float4*)&xin[(size_t)q1.x * 128 + f0];
        const float4 a3 = *(const float4*)&xin[(size_t)q1.z * 128 + f0];
        const float4 a4 = *(const float4*)&xin[(size_t)q2.x * 128 + f0];
        const float4 a5 = *(const float4*)&xin[(size_t)q2.z * 128 + f0];
        const float4 a6 = *(const float4*)&xin[(size_t)q3.x * 128 + f0];
        const float4 a7 = *(const float4*)&xin[(size_t)q3.z * 128 + f0];
        const float w0 = __int_as_float(q0.y), w1 = __int_as_float(q0.w);
        const float w2 = __int_as_float(q1.y), w3 = __int_as_float(q1.w);
        const float w4 = __int_as_float(q2.y), w5 = __int_as_float(q2.w);
        const float w6 = __int_as_float(q3.y), w7 = __int_as_float(q3.w);
        acc.x += w0 * a0.x + w1 * a1.x + w2 * a2.x + w3 * a3.x
               + w4 * a4.x + w5 * a5.x + w6 * a6.x + w7 * a7.x;
        acc.y += w0 * a0.y + w1 * a1.y + w2 * a2.y + w3 * a3.y
               + w4 * a4.y + w5 * a5.y + w6 * a6.y + w7 * a7.y;
        acc.z += w0 * a0.z + w1 * a1.z + w2 * a2.z + w3 * a3.z
               + w4 * a4.z + w5 * a5.z + w6 * a6.z + w7 * a7.z;
        acc.w += w0 * a0.w + w1 * a1.w + w2 * a2.w + w3 * a3.w
               + w4 * a4.w + w5 * a5.w + w6 * a6.w + w7 * a7.w;
      }
      float* bp = &xm[r * 128 + lane];
      atomicAdd(bp + 0,  acc.x);
      atomicAdd(bp + 32, acc.y);
      atomicAdd(bp + 64, acc.z);
      atomicAdd(bp + 96, acc.w);
    }
  }
  __syncthreads();

  // ---- stage 2: de-permute + finalize (1+eps)*x + agg/deg ----
  {
    float4 m[4];
#pragma unroll
    for (int q = 0; q < 4; ++q) {
      const int task = t + q * 256;             // 32 rows x 32 fgroups
      const int r = task >> 5;
      const int fg = task & 31;
      m[q].x = xm[r * 128 + fg];
      m[q].y = xm[r * 128 + 32 + fg];
      m[q].z = xm[r * 128 + 64 + fg];
      m[q].w = xm[r * 128 + 96 + fg];
    }
    __syncthreads();
#pragma unroll
    for (int q = 0; q < 4; ++q) {
      const int task = t + q * 256;
      const int r = task >> 5;
      const int fg = task & 31;
      const int f0 = fg * 4;
      const int node = nb + r;
      float4 v = make_float4(0.f, 0.f, 0.f, 0.f);
      if (node < n) {
        const int d = cnt[node];
        const float rdeg = 1.0f / (float)(d > 1 ? d : 1);
        const float4 xv = *(const float4*)&xin[(size_t)node * 128 + f0];
        v.x = epsv * xv.x + m[q].x * rdeg;
        v.y = epsv * xv.y + m[q].y * rdeg;
        v.z = epsv * xv.z + m[q].z * rdeg;
        v.w = epsv * xv.w + m[q].w * rdeg;
      }
      *(float4*)&xm[r * 128 + f0] = v;
    }
  }
  __syncthreads();

  // ---- stage 3: GEMM, thread tile = 4 rows x 4 features ----
  {
    const int fg = t & 31;
    const int rg = t >> 5;
    const int f0 = fg * 4;
    const int r0 = rg * 4;
    float4 acc[4];
#pragma unroll
    for (int r = 0; r < 4; ++r) acc[r] = make_float4(0.f, 0.f, 0.f, 0.f);
    for (int k = 0; k < 128; k += 4) {
      const float4 w0 = *(const float4*)&Wt[(k + 0) * 128 + f0];
      const float4 w1 = *(const float4*)&Wt[(k + 1) * 128 + f0];
      const float4 w2 = *(const float4*)&Wt[(k + 2) * 128 + f0];
      const float4 w3 = *(const float4*)&Wt[(k + 3) * 128 + f0];
#pragma unroll
      for (int r = 0; r < 4; ++r) {
        const float4 xv = *(const float4*)&xm[(r0 + r) * 128 + k];
        acc[r].x += xv.x * w0.x + xv.y * w1.x + xv.z * w2.x + xv.w * w3.x;
        acc[r].y += xv.x * w0.y + xv.y * w1.y + xv.z * w2.y + xv.w * w3.y;
        acc[r].z += xv.x * w0.z + xv.y * w1.z + xv.z * w2.z + xv.w * w3.z;
        acc[r].w += xv.x * w0.w + xv.y * w1.w + xv.z * w2.w + xv.w * w3.w;
      }
    }
    const float4 bv = *(const float4*)&bias[f0];
#pragma unroll
    for (int r = 0; r < 4; ++r) {
      const int node = nb + r0 + r;
      if (node < n) {
        float4 v;
        v.x = acc[r].x + bv.x;
        v.y = acc[r].y + bv.y;
        v.z = acc[r].z + bv.z;
        v.w = acc[r].w + bv.w;
        if (dorelu) {
          v.x = fmaxf(v.x, 0.f); v.y = fmaxf(v.y, 0.f);
          v.z = fmaxf(v.z, 0.f); v.w = fmaxf(v.w, 0.f);
        }
        if (zerorow0 && node == 0) { v.x = 0.f; v.y = 0.f; v.z = 0.f; v.w = 0.f; }
        *(float4*)&xout[(size_t)node * 128 + f0] = v;
      }
    }
  }
}

// One block (128 thr) per batch element: gather ing1/ing2/ctx into LDS, MLP 384->128->64->1.
__launch_bounds__(128, 4)
__global__ void final_kernel(const float* __restrict__ x2, const int* __restrict__ indices,
                             const float* __restrict__ Wc1t, const float* __restrict__ bc1,
                             const float* __restrict__ Wc2t, const float* __restrict__ bc2,
                             const float* __restrict__ Wc3, const float* __restrict__ bc3,
                             float* __restrict__ out) {
  __shared__ float ysm[384];
  __shared__ float h1s[128];
  const int b = blockIdx.x;
  const int t = threadIdx.x;
  const int* ind = indices + (size_t)b * 23;

  {
    const int i0 = ind[0];
    const int i1 = ind[1];
    ysm[t] = x2[(size_t)i0 * 128 + t];
    ysm[128 + t] = x2[(size_t)i1 * 128 + t];
    float cs = 0.f;
    int cc = 0;
#pragma unroll
    for (int j = 0; j < 20; ++j) {
      const int cj = ind[3 + j];
      cc += (cj > 0) ? 1 : 0;
      cs += x2[(size_t)cj * 128 + t];
    }
    ysm[256 + t] = cs / (float)(cc > 0 ? cc : 1);
  }
  __syncthreads();

  {
    float acc = bc1[t];
    for (int k = 0; k < 384; k += 4) {
      const float4 yv = *(const float4*)&ysm[k];
      acc += yv.x * Wc1t[(k + 0) * 128 + t];
      acc += yv.y * Wc1t[(k + 1) * 128 + t];
      acc += yv.z * Wc1t[(k + 2) * 128 + t];
      acc += yv.w * Wc1t[(k + 3) * 128 + t];
    }
    h1s[t] = fmaxf(acc, 0.f);
  }
  __syncthreads();

  if (t < 64) {
    float acc = bc2[t];
    for (int k = 0; k < 128; k += 4) {
      const float4 hv = *(const float4*)&h1s[k];
      acc += hv.x * Wc2t[(k + 0) * 64 + t];
      acc += hv.y * Wc2t[(k + 1) * 64 + t];
      acc += hv.z * Wc2t[(k + 2) * 64 + t];
      acc += hv.w * Wc2t[(k + 3) * 64 + t];
    }
    float v = fmaxf(acc, 0.f) * Wc3[t];
#pragma unroll
    for (int o = 32; o > 0; o >>= 1) v += __shfl_down(v, o);
    if (t == 0) out[b] = v + bc3[0];
  }
}

extern "C" void kernel_launch(void* const* d_in, const int* in_sizes, int n_in,
                              void* d_out, int out_size, void* d_ws, size_t ws_size,
                              hipStream_t stream) {
  const int* indices = (const int*)d_in[0];
  const int* src = (const int*)d_in[1];
  const int* dst = (const int*)d_in[2];
  const float* w = (const float*)d_in[3];
  const float* ndata = (const float*)d_in[4];
  const float* W1 = (const float*)d_in[5];
  const float* b1 = (const float*)d_in[6];
  const float* W2 = (const float*)d_in[7];
  const float* b2 = (const float*)d_in[8];
  const float* eps = (const float*)d_in[9];
  const float* Wc1 = (const float*)d_in[10];
  const float* bc1 = (const float*)d_in[11];
  const float* Wc2 = (const float*)d_in[12];
  const float* bc2 = (const float*)d_in[13];
  const float* Wc3 = (const float*)d_in[14];
  const float* bc3 = (const float*)d_in[15];
  float* out = (float*)d_out;

  const int E = in_sizes[1];
  const int N = in_sizes[4] / 128;
  const int B = in_sizes[0] / 23;

  char* ws = (char*)d_ws;
  size_t off = 0;
  auto alloc = [&](size_t bytes) -> char* {
    char* p = ws + off;
    off = (off + bytes + 255) & ~(size_t)255;
    return p;
  };
  const size_t Epad = (size_t)E + 8 * (size_t)N;   // worst-case padded edge count
  int* cnt = (int*)alloc((size_t)N * 4);
  int* prow = (int*)alloc((size_t)(N + 1) * 4);
  int* rank = (int*)alloc((size_t)E * 4);
  int* bsum = (int*)alloc(256 * 4);
  int2* epack = (int2*)alloc(Epad * 8);
  float* x1 = (float*)alloc((size_t)N * 128 * 4);
  float* x2 = (float*)alloc((size_t)N * 128 * 4);
  float* Wt1 = (float*)alloc(16384 * 4);
  float* Wt2 = (float*)alloc(16384 * 4);
  float* Wc1t = (float*)alloc(49152 * 4);
  float* Wc2t = (float*)alloc(8192 * 4);

  hipMemsetAsync(cnt, 0, (size_t)N * 4, stream);
  hipMemsetAsync(epack, 0, Epad * 8, stream);      // pad slots -> (src=0, w=0)

  prep_transpose<<<(90112 + 255) / 256, 256, 0, stream>>>(W1, W2, Wc1, Wc2, Wt1, Wt2, Wc1t, Wc2t);
  hist_kernel<<<(E + 255) / 256, 256, 0, stream>>>(dst, cnt, rank, E);
  const int nchunk = (N + 2047) / 2048;
  scan1_kernel<<<nchunk, 256, 0, stream>>>(cnt, prow, bsum, N);
  scan2_kernel<<<1, 64, 0, stream>>>(bsum, nchunk);
  scan3_kernel<<<(N + 255) / 256, 256, 0, stream>>>(prow, bsum, N, nchunk);
  scatter_kernel<<<(E + 255) / 256, 256, 0, stream>>>(src, dst, w, prow, rank, epack, E);

  const int nconv = (N + CONV_NPB - 1) / CONV_NPB;
  conv_kernel<<<nconv, 256, 0, stream>>>(ndata, x1, prow, cnt, epack, Wt1, b1, eps, 0, 1, 0, N);
  conv_kernel<<<nconv, 256, 0, stream>>>(x1, x2, prow, cnt, epack, Wt2, b2, eps, 1, 0, 1, N);

  final_kernel<<<B, 128, 0, stream>>>(x2, indices, Wc1t, bc1, Wc2t, bc2, Wc3, bc3, out);
}